// Round 2
// baseline (1025.933 us; speedup 1.0000x reference)
//
#include <hip/hip_runtime.h>
#include <stdint.h>

#define NQ 49      // queries (patch tokens)
#define MT 50      // tokens incl cls (keys)
#define NH 8
#define HD 32
#define NW 64
#define BWIN 4096  // total windows

typedef __attribute__((ext_vector_type(8))) short short8;
typedef __attribute__((ext_vector_type(4))) float f32x4;

__device__ __forceinline__ uint32_t f2u(float x){ union{float f;uint32_t u;}c; c.f=x; return c.u; }
__device__ __forceinline__ float u2f(uint32_t u){ union{float f;uint32_t u;}c; c.u=u; return c.f; }
// round-to-nearest-even fp32 -> bf16 bits (finite inputs only)
__device__ __forceinline__ uint32_t bf16rn(float x){
  uint32_t u = f2u(x);
  return (u + 0x7fffu + ((u >> 16) & 1u)) >> 16;
}
// truncation split: hi = top16(x), lo = rn(x - hi). Residual captures the
// truncation error; dropped ql*kl cross-term stays ~1e-4 << P-bf16 error.
__device__ __forceinline__ void bsplit(float x, uint32_t& hi, uint32_t& lo){
  uint32_t u = f2u(x);
  hi = u >> 16;
  lo = bf16rn(x - u2f(u & 0xffff0000u));
}

// ===== single fused kernel: mask+bias gather fused into score add ==========
// 1 wave per (window, head), 2 heads/block. NO workspace use (M2 eliminated).
__global__ __launch_bounds__(128, 4)
void winattn_kernel(const float* __restrict__ qkv,
                    const float* __restrict__ mask,
                    const float* __restrict__ bias_table,
                    const int*   __restrict__ rel_index,
                    float* __restrict__ out)
{
  // P (unnormalized probs) as bf16, 64x64 per wave, XOR-swizzled 16B chunks
  // (conflict-free b128 reads, no padding needed).
  __shared__ unsigned short sP[2][64 * 64];

  const int wv   = threadIdx.x >> 6;      // wave in block (= head parity)
  const int lane = threadIdx.x & 63;
  const int ln   = lane & 15;
  const int qd   = lane >> 4;             // quad 0..3

  const int id = blockIdx.x;
  const int b  = id >> 2;
  const int h  = ((id & 3) << 1) | wv;
  const int w  = b & (NW - 1);

  const float* base = qkv + (size_t)b * (MT * 3 * 256);
  const float scale = 0.17677669529663687f;  // 1/sqrt(32)

  // ---- K fragments: global -> regs, bf16 hi/lo split -----------------------
  short8 kh[4], kl[4];
#pragma unroll
  for (int u = 0; u < 4; ++u) {
    int n    = 16 * u + ln;
    int ktok = (n < MT ? n : MT - 1);
    const float* p = base + (size_t)ktok * 768 + 256 + h * HD + qd * 8;
    f32x4 e0 = *(const f32x4*)p;
    f32x4 e1 = *(const f32x4*)(p + 4);
#pragma unroll
    for (int j = 0; j < 8; ++j) {
      float x = (j < 4 ? e0[j] : e1[j - 4]);
      uint32_t hi, lo; bsplit(x, hi, lo);
      kh[u][j] = (short)(unsigned short)hi;
      kl[u][j] = (short)(unsigned short)lo;
    }
  }

  const float* mrow = mask + (size_t)w * NQ * MT;
  float rsumv[4][4];

  // ---- per Q-tile: load -> QK^T (3-term MFMA) -> +mask+bias -> softmax -> LDS
  // S lives only 16 regs at a time (was 64): peak pressure ~90 VGPR, no spill.
#pragma unroll
  for (int t = 0; t < 4; ++t) {
    int m   = 16 * t + ln;
    int tok = (m < NQ ? m : NQ - 1) + 1;       // +1 skips cls token
    const float* p = base + (size_t)tok * 768 + h * HD + qd * 8;
    f32x4 e0 = *(const f32x4*)p;
    f32x4 e1 = *(const f32x4*)(p + 4);
    short8 qh, ql;
#pragma unroll
    for (int j = 0; j < 8; ++j) {
      float x = (j < 4 ? e0[j] : e1[j - 4]) * scale;
      uint32_t hi, lo; bsplit(x, hi, lo);
      qh[j] = (short)(unsigned short)hi;
      ql[j] = (short)(unsigned short)lo;
    }

    f32x4 S[4];
#pragma unroll
    for (int u = 0; u < 4; ++u) {
      f32x4 a = {0.f, 0.f, 0.f, 0.f};
      a = __builtin_amdgcn_mfma_f32_16x16x32_bf16(qh, kh[u], a, 0, 0, 0);
      a = __builtin_amdgcn_mfma_f32_16x16x32_bf16(qh, kl[u], a, 0, 0, 0);
      a = __builtin_amdgcn_mfma_f32_16x16x32_bf16(ql, kh[u], a, 0, 0, 0);
      S[u] = a;
    }

#pragma unroll
    for (int r = 0; r < 4; ++r) {
      int i = 16 * t + 4 * qd + r;             // query row (C/D layout)
#pragma unroll
      for (int u = 0; u < 4; ++u) {
        int j = 16 * u + ln;
        if (j >= MT)      S[u][r] = -1e30f;    // pad keys
        else if (i < NQ) {
          float add = mrow[i * MT + j];        // L2-resident (627 KB total)
          if (j > 0)                           // cls column has no bias
            add += bias_table[rel_index[i * NQ + (j - 1)] * NH + h];  // L1-hit
          S[u][r] += add;
        }
      }
      float mx = fmaxf(fmaxf(S[0][r], S[1][r]), fmaxf(S[2][r], S[3][r]));
#pragma unroll
      for (int s = 1; s < 16; s <<= 1) mx = fmaxf(mx, __shfl_xor(mx, s, 16));
      int m7 = i & 7;
      float sum = 0.f;
#pragma unroll
      for (int u = 0; u < 4; ++u) {
        float pv = exp2f((S[u][r] - mx) * 1.4426950408889634f);
        sum += pv;
        int c = 16 * u + ln;
        int addr = i * 64 + ((((c >> 3) ^ m7) << 3) | (c & 7));
        sP[wv][addr] = (unsigned short)bf16rn(pv);
      }
#pragma unroll
      for (int s = 1; s < 16; s <<= 1) sum += __shfl_xor(sum, s, 16);
      rsumv[t][r] = sum;
    }
  }
  __syncthreads();

  // ---- V fragments (bf16 hi/lo) --------------------------------------------
  short8 vh[2][2], vl[2][2];   // [k-iter][d-tile]
#pragma unroll
  for (int kt = 0; kt < 2; ++kt) {
#pragma unroll
    for (int u2 = 0; u2 < 2; ++u2) {
#pragma unroll
      for (int j = 0; j < 8; ++j) {
        int k  = 32 * kt + 8 * qd + j;
        int d  = 16 * u2 + ln;
        int kc = (k < MT ? k : MT - 1);
        float x = base[(size_t)kc * 768 + 512 + h * HD + d];
        if (k >= MT) x = 0.f;
        uint32_t hi, lo; bsplit(x, hi, lo);
        vh[kt][u2][j] = (short)(unsigned short)hi;
        vl[kt][u2][j] = (short)(unsigned short)lo;
      }
    }
  }

  // ---- PV via MFMA: LDS read IS the A-fragment (bf16, swizzled) ------------
  f32x4 O[4][2];
#pragma unroll
  for (int t = 0; t < 4; ++t)
#pragma unroll
    for (int u2 = 0; u2 < 2; ++u2) O[t][u2] = (f32x4){0.f, 0.f, 0.f, 0.f};

#pragma unroll
  for (int kt = 0; kt < 2; ++kt) {
#pragma unroll
    for (int t = 0; t < 4; ++t) {
      int m = 16 * t + ln;
      int phys = ((4 * kt + qd) ^ (ln & 7));
      short8 ph = *(const short8*)&sP[wv][m * 64 + (phys << 3)];
#pragma unroll
      for (int u2 = 0; u2 < 2; ++u2) {
        f32x4 a = O[t][u2];
        a = __builtin_amdgcn_mfma_f32_16x16x32_bf16(ph, vh[kt][u2], a, 0, 0, 0);
        a = __builtin_amdgcn_mfma_f32_16x16x32_bf16(ph, vl[kt][u2], a, 0, 0, 0);
        O[t][u2] = a;
      }
    }
  }

  // ---- epilogue: normalize + store -----------------------------------------
#pragma unroll
  for (int t = 0; t < 4; ++t) {
#pragma unroll
    for (int r = 0; r < 4; ++r) {
      int row = 16 * t + 4 * qd + r;
      if (row >= NQ) continue;
      float inv = 1.0f / rsumv[t][r];
#pragma unroll
      for (int u2 = 0; u2 < 2; ++u2) {
        int d = 16 * u2 + ln;
        out[(((size_t)b * NQ + row) * NH + h) * HD + d] = O[t][u2][r] * inv;
      }
    }
  }
}

extern "C" void kernel_launch(void* const* d_in, const int* in_sizes, int n_in,
                              void* d_out, int out_size, void* d_ws, size_t ws_size,
                              hipStream_t stream) {
  (void)in_sizes; (void)n_in; (void)ws_size; (void)out_size; (void)d_ws;
  const float* qkv        = (const float*)d_in[0];
  const float* mask       = (const float*)d_in[1];
  const float* bias_table = (const float*)d_in[2];
  const int*   rel_index  = (const int*)d_in[3];
  float* out = (float*)d_out;

  winattn_kernel<<<BWIN * 4, 128, 0, stream>>>(qkv, mask, bias_table, rel_index, out);
}